// Round 8
// baseline (231.692 us; speedup 1.0000x reference)
//
#include <hip/hip_runtime.h>

typedef unsigned int u32;
typedef unsigned short u16;
typedef unsigned long long u64;
typedef __attribute__((ext_vector_type(8))) short short8;
typedef __attribute__((ext_vector_type(4))) float f32x4;
typedef __attribute__((ext_vector_type(4))) float fv4;

#define NB 8
#define NC 64
#define NH 376
#define NWID 1241
#define NPTS 30000
#define NDIN 80
#define NTOTP 240000
#define NBIN (NB*NH)            // 3008
#define HW_ ((size_t)NH*NWID)
#define CHW_ ((size_t)NC*HW_)

// workspace layout
#define OFF_WPROJ 0             // u16[48*64]
#define OFF_W1T   8192          // u16[64*96]
#define OFF_WBOT  24576        // u16[32*64]
#define OFF_CBIAS 28672        // float[48]
#define OFF_HIST  32768        // u32[NBIN]
#define OFF_OFF   45056        // u32[NBIN+1]
#define OFF_OFF2  57344        // u32[NBIN]
#define OFF_SORT  69632        // u32[NTOTP]
#define WS_NEED   ((size_t)69632 + (size_t)NTOTP*4)

__device__ __forceinline__ u16 f2bf(float f) {
    u32 u = __builtin_bit_cast(u32, f);
    return (u16)((u + 0x7FFFu + ((u >> 16) & 1u)) >> 16);
}
__device__ __forceinline__ float bf2f(u32 lo16) {
    return __builtin_bit_cast(float, lo16 << 16);
}
__device__ __forceinline__ u32 packbf2(float a, float b) {
    return (u32)f2bf(a) | ((u32)f2bf(b) << 16);
}
#define MFMA16(a,b,c) __builtin_amdgcn_mfma_f32_16x16x32_bf16(a, b, c, 0, 0, 0)

// ================= prep: bf16 weight tables + folded biases =================
__global__ void prep_kernel(const float* __restrict__ W1, const float* __restrict__ W2,
                            const float* __restrict__ b2, const float* __restrict__ Wc1,
                            const float* __restrict__ bc1, const float* __restrict__ Wc2,
                            const float* __restrict__ bc2,
                            u16* __restrict__ Wproj, u16* __restrict__ W1t,
                            u16* __restrict__ Wbot, float* __restrict__ cbias) {
    int t = blockIdx.x * 256 + threadIdx.x;
    if (t < 3072) {
        int j = t >> 6, ch = t & 63;
        float v = 0.f;
        if (j < 19) { for (int c = 0; c < 64; ++c) v += W2[ch * 64 + c] * Wc1[c * 19 + j]; }
        else if (j >= 20 && j < 39) v = Wc2[ch * 19 + (j - 20)];
        Wproj[t] = f2bf(v);
    } else if (t < 3072 + 6144) {
        int q = t - 3072; int c = q / 96, d = q % 96;
        W1t[q] = f2bf(d < 80 ? W1[d * 64 + c] : 0.f);
    } else if (t < 3072 + 6144 + 2048) {
        int q = t - 9216; int j = q >> 6, c = q & 63;
        float v = 0.f;
        if (j < 19) { for (int cc = 0; cc < 64; ++cc) v += W2[(64 + c) * 64 + cc] * Wc1[cc * 19 + j]; }
        Wbot[q] = f2bf(v);
    } else if (t < 3072 + 6144 + 2048 + 48) {
        int j = t - 11264;
        float v = 0.f;
        if (j < 19) { v = bc1[j]; for (int c = 0; c < 64; ++c) v += b2[c] * Wc1[c * 19 + j]; }
        else if (j >= 20 && j < 39) v = bc2[j - 20];
        cbias[j] = v;
    }
}

// ================= bucketing: counting sort of points by (b,h) ==============
__global__ void zero_kernel(u32* __restrict__ hist) {
    int t = blockIdx.x * 256 + threadIdx.x;
    if (t < NBIN) hist[t] = 0;
}
__global__ void hist_kernel(const int* __restrict__ idx, u32* __restrict__ hist) {
    int i = blockIdx.x * 256 + threadIdx.x;
    if (i >= NTOTP) return;
    int bin = (i / NPTS) * NH + idx[2 * i];
    atomicAdd(&hist[bin], 1u);
}
__global__ __launch_bounds__(256) void scan_kernel(const u32* __restrict__ hist,
        u32* __restrict__ off, u32* __restrict__ off2) {
    __shared__ u32 tsum[256];
    __shared__ u32 tpre[256];
    int t = threadIdx.x;
    u32 loc[12]; u32 s = 0;
    #pragma unroll
    for (int k = 0; k < 12; ++k) { int b = t * 12 + k; loc[k] = (b < NBIN) ? hist[b] : 0; s += loc[k]; }
    tsum[t] = s;
    __syncthreads();
    if (t == 0) { u32 r = 0; for (int i = 0; i < 256; ++i) { tpre[i] = r; r += tsum[i]; } off[NBIN] = r; }
    __syncthreads();
    u32 r = tpre[t];
    #pragma unroll
    for (int k = 0; k < 12; ++k) {
        int b = t * 12 + k;
        if (b < NBIN) { off[b] = r; off2[b] = r; r += loc[k]; }
    }
}
__global__ void scatter_kernel(const int* __restrict__ idx, u32* __restrict__ off2,
                               u32* __restrict__ sorted) {
    int i = blockIdx.x * 256 + threadIdx.x;
    if (i >= NTOTP) return;
    int bin = (i / NPTS) * NH + idx[2 * i];
    u32 slot = atomicAdd(&off2[bin], 1u);
    sorted[slot] = (u32)i;
}

// ================= main: per-(b,h) slab in LDS, serve its points ============
// LDS [pos][ch] stride 72 u16 (144B rows, 16B-aligned) -> bfrag = ds_read_b128.
__global__ __launch_bounds__(256) void bucket_kernel(
        const float* __restrict__ feats, const float* __restrict__ fusion,
        const int* __restrict__ idx, const float* __restrict__ b1,
        const u16* __restrict__ Wproj, const u16* __restrict__ W1t,
        const u16* __restrict__ Wbot, const float* __restrict__ cbias,
        const u32* __restrict__ off, const u32* __restrict__ sorted,
        float* __restrict__ out) {
    __shared__ __align__(16) u16 ldsA[376][72];    // 54.1 KB
    __shared__ __align__(16) u32 sbuf[4][16][44];  // 11.3 KB per-wave staging
    int tid = threadIdx.x;
    int lane = tid & 63, wid = tid >> 6;
    int l15 = lane & 15, l4 = lane >> 4;
    int bin = blockIdx.x;
    u32 base = off[bin], end = off[bin + 1];
    if (base == end) return;
    int b = bin / NH, h = bin % NH;
    const float* rowbase = feats + (size_t)b * CHW_ + (size_t)h * NWID;

    // ---- stage: wave wid loads channels wid*16..+15, 376 pos each (fv4 runs)
    #pragma unroll
    for (int it = 0; it < 16; ++it) {
        int c = wid * 16 + it;
        const float* src = rowbase + (size_t)c * HW_;
        fv4 v = *(const fv4*)(src + lane * 4);
        int p0 = lane * 4;
        ldsA[p0 + 0][c] = f2bf(v.x); ldsA[p0 + 1][c] = f2bf(v.y);
        ldsA[p0 + 2][c] = f2bf(v.z); ldsA[p0 + 3][c] = f2bf(v.w);
        if (lane < 30) {
            fv4 w = *(const fv4*)(src + 256 + lane * 4);
            int p1 = 256 + lane * 4;
            ldsA[p1 + 0][c] = f2bf(w.x); ldsA[p1 + 1][c] = f2bf(w.y);
            ldsA[p1 + 2][c] = f2bf(w.z); ldsA[p1 + 3][c] = f2bf(w.w);
        }
    }

    // ---- weights into registers (overlaps staging latency)
    short8 wf[3][2];
    #pragma unroll
    for (int mt = 0; mt < 3; ++mt)
        #pragma unroll
        for (int kt = 0; kt < 2; ++kt)
            wf[mt][kt] = *(const short8*)(Wproj + (mt * 16 + l15) * 64 + kt * 32 + l4 * 8);
    short8 w1f[4][3];
    #pragma unroll
    for (int mt = 0; mt < 4; ++mt)
        #pragma unroll
        for (int kt = 0; kt < 3; ++kt)
            w1f[mt][kt] = *(const short8*)(W1t + (mt * 16 + l15) * 96 + kt * 32 + l4 * 8);
    short8 wbf[2][2];
    #pragma unroll
    for (int mt = 0; mt < 2; ++mt)
        #pragma unroll
        for (int kt = 0; kt < 2; ++kt)
            wbf[mt][kt] = *(const short8*)(Wbot + (mt * 16 + l15) * 64 + kt * 32 + l4 * 8);
    float bias[3][4], b1r[4][4];
    #pragma unroll
    for (int mt = 0; mt < 3; ++mt)
        #pragma unroll
        for (int q = 0; q < 4; ++q)
            bias[mt][q] = cbias[mt * 16 + l4 * 4 + q];
    #pragma unroll
    for (int mt = 0; mt < 4; ++mt)
        #pragma unroll
        for (int q = 0; q < 4; ++q)
            b1r[mt][q] = b1[mt * 16 + l4 * 4 + q];

    __syncthreads();

    u32* myl = &sbuf[wid][0][0];
    int ngroups = (int)(end - base + 15) >> 4;
    for (int g = wid; g < ngroups; g += 4) {
        u32 sp = base + (u32)g * 16 + (u32)l15;
        bool valid = sp < end;
        int ip = (int)sorted[valid ? sp : base];
        u32 wp = (u32)idx[2 * ip + 1];

        // bfrag from staged slab (one b128 per kt)
        short8 bfrag[2];
        bfrag[0] = *(const short8*)&ldsA[wp][l4 * 8];
        bfrag[1] = *(const short8*)&ldsA[wp][32 + l4 * 8];

        // folded-A + Wc2 contribution
        f32x4 acc[3];
        #pragma unroll
        for (int mt = 0; mt < 3; ++mt) {
            if (mt == 2 && l4 >= 2) { f32x4 z = {0.f, 0.f, 0.f, 0.f}; acc[mt] = z; }
            else { f32x4 a = {bias[mt][0], bias[mt][1], bias[mt][2], bias[mt][3]}; acc[mt] = a; }
        }
        #pragma unroll
        for (int kt = 0; kt < 2; ++kt)
            #pragma unroll
            for (int mt = 0; mt < 3; ++mt)
                acc[mt] = MFMA16(wf[mt][kt], bfrag[kt], acc[mt]);

        // GEMM1: f1 = relu(X@W1+b1)
        const float* frow = fusion + (size_t)ip * NDIN;
        f32x4 c1[4];
        #pragma unroll
        for (int mt = 0; mt < 4; ++mt) {
            f32x4 a = {b1r[mt][0], b1r[mt][1], b1r[mt][2], b1r[mt][3]};
            c1[mt] = a;
        }
        #pragma unroll
        for (int kt = 0; kt < 3; ++kt) {
            short8 xf = {0, 0, 0, 0, 0, 0, 0, 0};
            int d0 = kt * 32 + l4 * 8;
            if (d0 < 80) {
                fv4 a = *(const fv4*)(frow + d0);
                fv4 bq = *(const fv4*)(frow + d0 + 4);
                short8 s;
                s[0] = (short)f2bf(a.x);  s[1] = (short)f2bf(a.y);
                s[2] = (short)f2bf(a.z);  s[3] = (short)f2bf(a.w);
                s[4] = (short)f2bf(bq.x); s[5] = (short)f2bf(bq.y);
                s[6] = (short)f2bf(bq.z); s[7] = (short)f2bf(bq.w);
                xf = s;
            }
            #pragma unroll
            for (int mt = 0; mt < 4; ++mt) c1[mt] = MFMA16(w1f[mt][kt], xf, c1[mt]);
        }
        // relu -> bf16 -> swizzled per-wave LDS rows
        #pragma unroll
        for (int mt = 0; mt < 4; ++mt) {
            float x0 = fmaxf(c1[mt][0], 0.f), x1 = fmaxf(c1[mt][1], 0.f);
            float x2 = fmaxf(c1[mt][2], 0.f), x3 = fmaxf(c1[mt][3], 0.f);
            u32 lo = packbf2(x0, x1), hi = packbf2(x2, x3);
            int c0 = mt * 16 + l4 * 4;
            int gsw = (c0 >> 3) ^ (l15 & 7);
            *(u64*)(myl + l15 * 44 + gsw * 4 + ((c0 & 4) >> 1)) = (u64)lo | ((u64)hi << 32);
        }
        // GEMM2: += Wbot . f1^T
        #pragma unroll
        for (int kt = 0; kt < 2; ++kt) {
            int gsw = (kt * 4 + l4) ^ (l15 & 7);
            short8 f1f = *(const short8*)(myl + l15 * 44 + gsw * 4);
            #pragma unroll
            for (int mt = 0; mt < 2; ++mt) acc[mt] = MFMA16(wbf[mt][kt], f1f, acc[mt]);
        }
        // stage results to row l15 (overwrites f1 region; same-wave in-order DS)
        #pragma unroll
        for (int mt = 0; mt < 3; ++mt) {
            if (mt == 2 && l4 >= 2) continue;
            *(f32x4*)(myl + l15 * 44 + mt * 16 + l4 * 4) = acc[mt];
        }
        // per-point stores: 4 l4-lanes cover 19+19 floats of point l15
        if (valid) {
            float* o1 = out + (size_t)ip * 19;
            float* o2 = out + (size_t)NTOTP * 19 + (size_t)ip * 19;
            #pragma unroll
            for (int s5 = 0; s5 < 5; ++s5) {
                int j = l4 * 5 + s5;
                if (j < 19) {
                    o1[j] = __builtin_bit_cast(float, myl[l15 * 44 + j]);
                    o2[j] = __builtin_bit_cast(float, myl[l15 * 44 + 20 + j]);
                }
            }
        }
    }
}

// ================= fallback (tiny ws): direct path ==========================
__global__ void precompute_old(const float* __restrict__ W2, const float* __restrict__ b2,
                               const float* __restrict__ Wc1, const float* __restrict__ bc1,
                               float* __restrict__ wsA, float* __restrict__ wsc1) {
    int t = blockIdx.x * 256 + threadIdx.x;
    if (t < 128 * 20) {
        int k = t / 20, j = t % 20;
        float v = 0.f;
        if (j < 19) for (int c = 0; c < 64; ++c) v += W2[k * 64 + c] * Wc1[c * 19 + j];
        wsA[t] = v;
    } else if (t < 128 * 20 + 20) {
        int j = t - 128 * 20;
        float v = 0.f;
        if (j < 19) { v = bc1[j]; for (int c = 0; c < 64; ++c) v += b2[c] * Wc1[c * 19 + j]; }
        wsc1[j] = v;
    }
}

__device__ __forceinline__ void fma4o(float4& a, float s, const float4 b) {
    a.x = fmaf(s, b.x, a.x); a.y = fmaf(s, b.y, a.y);
    a.z = fmaf(s, b.z, a.z); a.w = fmaf(s, b.w, a.w);
}

__global__ __launch_bounds__(256) void fused_old(
    const float* __restrict__ feats, const float* __restrict__ fusion,
    const int* __restrict__ idx, const float* __restrict__ W1, const float* __restrict__ b1,
    const float* __restrict__ Wc2, const float* __restrict__ bc2,
    const float* __restrict__ wsA, const float* __restrict__ wsc1, float* __restrict__ out) {
    __shared__ __align__(16) float sW1[80 * 64];
    __shared__ __align__(16) float sA[128 * 20];
    __shared__ __align__(16) float sWc2[64 * 20];
    __shared__ __align__(16) float sb1[64];
    __shared__ __align__(16) float sc1[20];
    __shared__ __align__(16) float sbc2[20];
    int tid = threadIdx.x;
    for (int t = tid; t < 80 * 64; t += 256) sW1[t] = W1[t];
    for (int t = tid; t < 128 * 20; t += 256) sA[t] = wsA[t];
    for (int t = tid; t < 64 * 20; t += 256) {
        int k = t / 20, j = t % 20;
        sWc2[t] = (j < 19) ? Wc2[k * 19 + j] : 0.f;
    }
    if (tid < 64) sb1[tid] = b1[tid];
    if (tid < 20) sc1[tid] = wsc1[tid];
    if (tid < 20) sbc2[tid] = (tid < 19) ? bc2[tid] : 0.f;
    __syncthreads();
    int i0 = blockIdx.x * 256 + tid;
    bool act = (i0 < NTOTP);
    int i = act ? i0 : 0;
    int b = i / NPTS;
    int2 hw = ((const int2*)idx)[i];
    float4 f14[16];
    #pragma unroll
    for (int c4 = 0; c4 < 16; ++c4) f14[c4] = ((const float4*)sb1)[c4];
    const float4* fu4 = (const float4*)(fusion + (size_t)i * NDIN);
    for (int d4 = 0; d4 < NDIN / 4; ++d4) {
        float4 x = fu4[d4];
        const float* wr = sW1 + d4 * 256;
        #pragma unroll
        for (int c4 = 0; c4 < 16; ++c4) {
            fma4o(f14[c4], x.x, *(const float4*)(wr + c4 * 4));
            fma4o(f14[c4], x.y, *(const float4*)(wr + 64 + c4 * 4));
            fma4o(f14[c4], x.z, *(const float4*)(wr + 128 + c4 * 4));
            fma4o(f14[c4], x.w, *(const float4*)(wr + 192 + c4 * 4));
        }
    }
    #pragma unroll
    for (int c4 = 0; c4 < 16; ++c4) {
        f14[c4].x = fmaxf(f14[c4].x, 0.f); f14[c4].y = fmaxf(f14[c4].y, 0.f);
        f14[c4].z = fmaxf(f14[c4].z, 0.f); f14[c4].w = fmaxf(f14[c4].w, 0.f);
    }
    float4 s14[5], s24[5];
    #pragma unroll
    for (int j4 = 0; j4 < 5; ++j4) { s14[j4] = ((const float4*)sc1)[j4]; s24[j4] = ((const float4*)sbc2)[j4]; }
    const float* fb = feats + (size_t)b * CHW_ + (size_t)hw.x * NWID + hw.y;
    for (int k = 0; k < 64; ++k) {
        float g = fb[(size_t)k * HW_];
        const float4* ar = (const float4*)(sA + k * 20);
        const float4* cr = (const float4*)(sWc2 + k * 20);
        #pragma unroll
        for (int j4 = 0; j4 < 5; ++j4) { fma4o(s14[j4], g, ar[j4]); fma4o(s24[j4], g, cr[j4]); }
    }
    const float* f1s = (const float*)f14;
    for (int k = 0; k < 64; ++k) {
        float g = f1s[k];
        const float4* ar = (const float4*)(sA + (64 + k) * 20);
        #pragma unroll
        for (int j4 = 0; j4 < 5; ++j4) fma4o(s14[j4], g, ar[j4]);
    }
    if (act) {
        float* o1 = out + (size_t)i * 19;
        float* o2 = out + (size_t)NTOTP * 19 + (size_t)i * 19;
        const float* s1s = (const float*)s14;
        const float* s2s = (const float*)s24;
        #pragma unroll
        for (int j = 0; j < 19; ++j) o1[j] = s1s[j];
        #pragma unroll
        for (int j = 0; j < 19; ++j) o2[j] = s2s[j];
    }
}

// ================= launch ====================================================
extern "C" void kernel_launch(void* const* d_in, const int* in_sizes, int n_in,
                              void* d_out, int out_size, void* d_ws, size_t ws_size,
                              hipStream_t stream) {
    const float* feats  = (const float*)d_in[0];
    const float* fusion = (const float*)d_in[1];
    const int*   idx    = (const int*)d_in[2];
    const float* W1  = (const float*)d_in[3];
    const float* b1  = (const float*)d_in[4];
    const float* W2  = (const float*)d_in[5];
    const float* b2  = (const float*)d_in[6];
    const float* Wc1 = (const float*)d_in[7];
    const float* bc1 = (const float*)d_in[8];
    const float* Wc2 = (const float*)d_in[9];
    const float* bc2 = (const float*)d_in[10];
    float* out = (float*)d_out;
    char* ws = (char*)d_ws;

    if (ws_size >= WS_NEED) {
        u16*   Wproj  = (u16*)(ws + OFF_WPROJ);
        u16*   W1t    = (u16*)(ws + OFF_W1T);
        u16*   Wbot   = (u16*)(ws + OFF_WBOT);
        float* cbias  = (float*)(ws + OFF_CBIAS);
        u32*   hist   = (u32*)(ws + OFF_HIST);
        u32*   offs   = (u32*)(ws + OFF_OFF);
        u32*   offs2  = (u32*)(ws + OFF_OFF2);
        u32*   sorted = (u32*)(ws + OFF_SORT);
        prep_kernel<<<45, 256, 0, stream>>>(W1, W2, b2, Wc1, bc1, Wc2, bc2,
                                            Wproj, W1t, Wbot, cbias);
        zero_kernel<<<12, 256, 0, stream>>>(hist);
        hist_kernel<<<(NTOTP + 255) / 256, 256, 0, stream>>>(idx, hist);
        scan_kernel<<<1, 256, 0, stream>>>(hist, offs, offs2);
        scatter_kernel<<<(NTOTP + 255) / 256, 256, 0, stream>>>(idx, offs2, sorted);
        bucket_kernel<<<NBIN, 256, 0, stream>>>(feats, fusion, idx, b1, Wproj, W1t,
                                                Wbot, cbias, offs, sorted, out);
    } else {
        float* wsA  = (float*)ws;
        float* wsc1 = wsA + 128 * 20;
        precompute_old<<<11, 256, 0, stream>>>(W2, b2, Wc1, bc1, wsA, wsc1);
        fused_old<<<(NTOTP + 255) / 256, 256, 0, stream>>>(feats, fusion, idx, W1, b1,
                                                           Wc2, bc2, wsA, wsc1, out);
    }
}

// Round 9
// 207.650 us; speedup vs baseline: 1.1158x; 1.1158x over previous
//
#include <hip/hip_runtime.h>

typedef unsigned int u32;
typedef unsigned short u16;
typedef unsigned long long u64;
typedef __attribute__((ext_vector_type(8))) short short8;
typedef __attribute__((ext_vector_type(4))) float f32x4;
typedef __attribute__((ext_vector_type(4))) float fv4;

#define NB 8
#define NC 64
#define NH 376
#define NWID 1241
#define NPTS 30000
#define NDIN 80
#define NTOTP 240000
#define PPB 141376              // 376*376 positions per sample
#define NPOS 1131008            // 8*PPB  (multiple of 256)
#define HW_ ((size_t)NH*NWID)
#define CHW_ ((size_t)NC*HW_)

// workspace layout (new path)
#define OFF_WPROJ 0             // u16[48*64]
#define OFF_W1T   8192          // u16[64*96]
#define OFF_WBOT  24576         // u16[32*64]
#define OFF_CBIAS 28672         // float[48]
#define OFF_PROJ  32768         // u16[NPOS][40]  (80B row per position)
#define WS_NEED   ((size_t)32768 + (size_t)NPOS*40*2)

__device__ __forceinline__ u16 f2bf(float f) {
    u32 u = __builtin_bit_cast(u32, f);
    return (u16)((u + 0x7FFFu + ((u >> 16) & 1u)) >> 16);
}
__device__ __forceinline__ float bf2f(u32 lo16) {
    return __builtin_bit_cast(float, lo16 << 16);
}
__device__ __forceinline__ u32 packbf2(float a, float b) {
    return (u32)f2bf(a) | ((u32)f2bf(b) << 16);
}
#define MFMA16(a,b,c) __builtin_amdgcn_mfma_f32_16x16x32_bf16(a, b, c, 0, 0, 0)

// ================= prep: build bf16 weight tables + folded biases ===========
__global__ void prep_kernel(const float* __restrict__ W1, const float* __restrict__ W2,
                            const float* __restrict__ b2, const float* __restrict__ Wc1,
                            const float* __restrict__ bc1, const float* __restrict__ Wc2,
                            const float* __restrict__ bc2,
                            u16* __restrict__ Wproj, u16* __restrict__ W1t,
                            u16* __restrict__ Wbot, float* __restrict__ cbias) {
    int t = blockIdx.x * 256 + threadIdx.x;
    if (t < 3072) {
        int j = t >> 6, ch = t & 63;
        float v = 0.f;
        if (j < 19) { for (int c = 0; c < 64; ++c) v += W2[ch * 64 + c] * Wc1[c * 19 + j]; }
        else if (j >= 20 && j < 39) v = Wc2[ch * 19 + (j - 20)];
        Wproj[t] = f2bf(v);
    } else if (t < 3072 + 6144) {
        int q = t - 3072; int c = q / 96, d = q % 96;
        W1t[q] = f2bf(d < 80 ? W1[d * 64 + c] : 0.f);
    } else if (t < 3072 + 6144 + 2048) {
        int q = t - 9216; int j = q >> 6, c = q & 63;
        float v = 0.f;
        if (j < 19) { for (int cc = 0; cc < 64; ++cc) v += W2[(64 + c) * 64 + cc] * Wc1[cc * 19 + j]; }
        Wbot[q] = f2bf(v);
    } else if (t < 3072 + 6144 + 2048 + 48) {
        int j = t - 11264;
        float v = 0.f;
        if (j < 19) { v = bc1[j]; for (int c = 0; c < 64; ++c) v += b2[c] * Wc1[c * 19 + j]; }
        else if (j >= 20 && j < 39) v = bc2[j - 20];
        cbias[j] = v;
    }
}

// ================= projection: block stages [64ch][256pos] in LDS ===========
// dwordx4 stage loads (1KB/instr coalescing), fully unrolled (16KB/wave in
// flight); bijective XCD swizzle so each XCD sweeps contiguous position space.
#define PROJ_NWG (NPOS / 256)   // 4418
__global__ __launch_bounds__(256) void proj_kernel(const float* __restrict__ feats,
        const u16* __restrict__ Wproj, const float* __restrict__ cbias,
        u16* __restrict__ proj) {
    __shared__ __align__(16) u16 ldsA[64][264];   // 33.8 KB
    __shared__ __align__(16) u32 sst[4][16][20];  // 5 KB per-wave output staging
    int tid = threadIdx.x;
    int lane = tid & 63, wid = tid >> 6;
    int l15 = lane & 15, l4 = lane >> 4;
    // bijective XCD-aware swizzle (m204): q=nwg/8, r=nwg%8
    int orig = blockIdx.x;
    {
        const int q = PROJ_NWG / 8, r = PROJ_NWG % 8;
        int xcd = orig & 7, lid = orig >> 3;
        orig = (xcd < r ? xcd * (q + 1) : r * (q + 1) + (xcd - r) * q) + lid;
    }
    int pblk0 = orig * 256;

    // ---- stage: 16 channels per wave, 256 positions, one dwordx4 per lane/ch
    {
        u32 p0 = (u32)(pblk0 + lane * 4);
        u32 b = p0 / PPB;                 // float4-span never crosses b/h (PPB%4==0, 376%4==0)
        u32 r = p0 - b * PPB;
        u32 h = r / 376u, w = r - h * 376u;
        const float* base0 = feats + (size_t)b * CHW_ + (size_t)h * NWID + w;
        #pragma unroll
        for (int it = 0; it < 16; ++it) {
            int c = wid * 16 + it;
            fv4 v = __builtin_nontemporal_load((const fv4*)(base0 + (size_t)c * HW_));
            u64 pk = (u64)packbf2(v.x, v.y) | ((u64)packbf2(v.z, v.w) << 32);
            *(u64*)&ldsA[c][lane * 4] = pk;
        }
    }
    __syncthreads();

    // ---- weight fragments + bias
    short8 wf[3][2];
    #pragma unroll
    for (int mt = 0; mt < 3; ++mt)
        #pragma unroll
        for (int kt = 0; kt < 2; ++kt)
            wf[mt][kt] = *(const short8*)(Wproj + (mt * 16 + l15) * 64 + kt * 32 + l4 * 8);
    float bias[3][4];
    #pragma unroll
    for (int mt = 0; mt < 3; ++mt)
        #pragma unroll
        for (int q = 0; q < 4; ++q)
            bias[mt][q] = cbias[mt * 16 + l4 * 4 + q];

    // ---- compute: wave owns positions [wid*64, wid*64+64)
    #pragma unroll 1
    for (int nt = 0; nt < 4; ++nt) {
        int lp = wid * 64 + nt * 16 + l15;         // local position (this lane's column)
        short8 bfrag[2];
        #pragma unroll
        for (int kt = 0; kt < 2; ++kt) {
            int ch0 = kt * 32 + l4 * 8;
            short8 s;
            #pragma unroll
            for (int e = 0; e < 8; ++e) s[e] = (short)ldsA[ch0 + e][lp];
            bfrag[kt] = s;
        }
        f32x4 acc[3];
        #pragma unroll
        for (int mt = 0; mt < 3; ++mt) {
            f32x4 a = {bias[mt][0], bias[mt][1], bias[mt][2], bias[mt][3]};
            acc[mt] = a;
        }
        #pragma unroll
        for (int kt = 0; kt < 2; ++kt)
            #pragma unroll
            for (int mt = 0; mt < 3; ++mt)
                acc[mt] = MFMA16(wf[mt][kt], bfrag[kt], acc[mt]);
        // stage row slices into per-wave LDS: row l15, word mt*8+l4*2
        #pragma unroll
        for (int mt = 0; mt < 3; ++mt) {
            if (mt == 2 && l4 >= 2) continue;
            uint2 st;
            st.x = packbf2(acc[mt][0], acc[mt][1]);
            st.y = packbf2(acc[mt][2], acc[mt][3]);
            *(uint2*)&sst[wid][l15][mt * 8 + l4 * 2] = st;
        }
        // cooperative coalesced store: 16 rows x 80B = 1280B contiguous
        const u32* s0 = &sst[wid][0][0];
        u32* dst = (u32*)(proj + (size_t)(pblk0 + wid * 64 + nt * 16) * 40);
        #pragma unroll
        for (int s = 0; s < 5; ++s) dst[lane + s * 64] = s0[lane + s * 64];
    }
}

// ================= fused: f1 = relu(X@W1+b1); S^T = Wbot.f1^T + gather(proj) =
__global__ __launch_bounds__(256) void fused2_kernel(const float* __restrict__ fusion,
        const int* __restrict__ idx, const float* __restrict__ b1,
        const u16* __restrict__ W1t, const u16* __restrict__ Wbot,
        const u16* __restrict__ proj, float* __restrict__ out) {
    __shared__ __align__(16) u32 sbuf[4][16][44];   // per-wave rows: f1 relayout then output staging
    int tid = threadIdx.x;
    int lane = tid & 63, wid = tid >> 6;
    int l15 = lane & 15, l4 = lane >> 4;
    int t = blockIdx.x * 4 + wid;                   // wave id; 7500 waves exactly
    int i0 = t * 32;

    short8 w1f[4][3];
    #pragma unroll
    for (int mt = 0; mt < 4; ++mt)
        #pragma unroll
        for (int kt = 0; kt < 3; ++kt)
            w1f[mt][kt] = *(const short8*)(W1t + (mt * 16 + l15) * 96 + kt * 32 + l4 * 8);
    short8 wbf[2][2];
    #pragma unroll
    for (int mt = 0; mt < 2; ++mt)
        #pragma unroll
        for (int kt = 0; kt < 2; ++kt)
            wbf[mt][kt] = *(const short8*)(Wbot + (mt * 16 + l15) * 64 + kt * 32 + l4 * 8);
    float b1r[4][4];
    #pragma unroll
    for (int mt = 0; mt < 4; ++mt)
        #pragma unroll
        for (int q = 0; q < 4; ++q)
            b1r[mt][q] = b1[mt * 16 + l4 * 4 + q];

    u32* myl = &sbuf[wid][0][0];
    #pragma unroll 1
    for (int nt = 0; nt < 2; ++nt) {
        int ipb = i0 + nt * 16;
        int ip = ipb + l15;                         // this lane's column point
        u64 hv = __builtin_nontemporal_load((const u64*)idx + ip);
        u32 hh = (u32)hv, ww = (u32)(hv >> 32);
        size_t pos = ((size_t)(u32)(ip / NPTS) * 376 + hh) * 376 + ww;
        const u16* prow = proj + pos * 40;
        f32x4 acc[3];
        #pragma unroll
        for (int mt = 0; mt < 3; ++mt) {
            if (mt == 2 && l4 >= 2) { f32x4 z = {0.f, 0.f, 0.f, 0.f}; acc[mt] = z; }
            else {
                uint2 v = *(const uint2*)(prow + mt * 16 + l4 * 4);
                f32x4 a = {bf2f(v.x & 0xffffu), bf2f(v.x >> 16),
                           bf2f(v.y & 0xffffu), bf2f(v.y >> 16)};
                acc[mt] = a;
            }
        }
        // GEMM1: C1^T[c][pos] = W1t . X^T
        const float* frow = fusion + (size_t)ip * NDIN;
        f32x4 c1[4];
        #pragma unroll
        for (int mt = 0; mt < 4; ++mt) {
            f32x4 a = {b1r[mt][0], b1r[mt][1], b1r[mt][2], b1r[mt][3]};
            c1[mt] = a;
        }
        #pragma unroll
        for (int kt = 0; kt < 3; ++kt) {
            short8 xf = {0, 0, 0, 0, 0, 0, 0, 0};
            int d0 = kt * 32 + l4 * 8;
            if (d0 < 80) {
                fv4 a = __builtin_nontemporal_load((const fv4*)(frow + d0));
                fv4 bq = __builtin_nontemporal_load((const fv4*)(frow + d0 + 4));
                short8 s;
                s[0] = (short)f2bf(a.x);  s[1] = (short)f2bf(a.y);
                s[2] = (short)f2bf(a.z);  s[3] = (short)f2bf(a.w);
                s[4] = (short)f2bf(bq.x); s[5] = (short)f2bf(bq.y);
                s[6] = (short)f2bf(bq.z); s[7] = (short)f2bf(bq.w);
                xf = s;
            }
            #pragma unroll
            for (int mt = 0; mt < 4; ++mt) c1[mt] = MFMA16(w1f[mt][kt], xf, c1[mt]);
        }
        // relu -> bf16 -> swizzled LDS [pos][c] (rows stride 44 words)
        #pragma unroll
        for (int mt = 0; mt < 4; ++mt) {
            float x0 = fmaxf(c1[mt][0], 0.f), x1 = fmaxf(c1[mt][1], 0.f);
            float x2 = fmaxf(c1[mt][2], 0.f), x3 = fmaxf(c1[mt][3], 0.f);
            u32 lo = packbf2(x0, x1), hi = packbf2(x2, x3);
            int c0 = mt * 16 + l4 * 4;
            int gsw = (c0 >> 3) ^ (l15 & 7);
            *(u64*)(myl + l15 * 44 + gsw * 4 + ((c0 & 4) >> 1)) = (u64)lo | ((u64)hi << 32);
        }
        // GEMM2: S^T += Wbot . f1^T
        #pragma unroll
        for (int kt = 0; kt < 2; ++kt) {
            int gsw = (kt * 4 + l4) ^ (l15 & 7);
            short8 f1f = *(const short8*)(myl + l15 * 44 + gsw * 4);
            #pragma unroll
            for (int mt = 0; mt < 2; ++mt) acc[mt] = MFMA16(wbf[mt][kt], f1f, acc[mt]);
        }
        // stage outputs to LDS rows (overwrites f1 region; same-wave in-order DS)
        #pragma unroll
        for (int mt = 0; mt < 3; ++mt) {
            if (mt == 2 && l4 >= 2) continue;
            *(f32x4*)(myl + l15 * 44 + mt * 16 + l4 * 4) = acc[mt];
        }
        // cooperative coalesced write: 16 rows x 19 floats per head
        size_t o1 = (size_t)ipb * 19;
        #pragma unroll
        for (int s = 0; s < 5; ++s) {
            int f = lane + s * 64;
            if (f < 304) {
                u32 rr = (u32)f / 19u;
                u32 jj = (u32)f - rr * 19u;
                float v1 = __builtin_bit_cast(float, myl[rr * 44 + jj]);
                float v2 = __builtin_bit_cast(float, myl[rr * 44 + 20 + jj]);
                __builtin_nontemporal_store(v1, out + o1 + f);
                __builtin_nontemporal_store(v2, out + (size_t)NTOTP * 19 + o1 + f);
            }
        }
    }
}

// ================= fallback (tiny ws): direct path ==========================
__global__ void precompute_old(const float* __restrict__ W2, const float* __restrict__ b2,
                               const float* __restrict__ Wc1, const float* __restrict__ bc1,
                               float* __restrict__ wsA, float* __restrict__ wsc1) {
    int t = blockIdx.x * 256 + threadIdx.x;
    if (t < 128 * 20) {
        int k = t / 20, j = t % 20;
        float v = 0.f;
        if (j < 19) for (int c = 0; c < 64; ++c) v += W2[k * 64 + c] * Wc1[c * 19 + j];
        wsA[t] = v;
    } else if (t < 128 * 20 + 20) {
        int j = t - 128 * 20;
        float v = 0.f;
        if (j < 19) { v = bc1[j]; for (int c = 0; c < 64; ++c) v += b2[c] * Wc1[c * 19 + j]; }
        wsc1[j] = v;
    }
}

__device__ __forceinline__ void fma4o(float4& a, float s, const float4 b) {
    a.x = fmaf(s, b.x, a.x); a.y = fmaf(s, b.y, a.y);
    a.z = fmaf(s, b.z, a.z); a.w = fmaf(s, b.w, a.w);
}

__global__ __launch_bounds__(256) void fused_old(
    const float* __restrict__ feats, const float* __restrict__ fusion,
    const int* __restrict__ idx, const float* __restrict__ W1, const float* __restrict__ b1,
    const float* __restrict__ Wc2, const float* __restrict__ bc2,
    const float* __restrict__ wsA, const float* __restrict__ wsc1, float* __restrict__ out) {
    __shared__ __align__(16) float sW1[80 * 64];
    __shared__ __align__(16) float sA[128 * 20];
    __shared__ __align__(16) float sWc2[64 * 20];
    __shared__ __align__(16) float sb1[64];
    __shared__ __align__(16) float sc1[20];
    __shared__ __align__(16) float sbc2[20];
    int tid = threadIdx.x;
    for (int t = tid; t < 80 * 64; t += 256) sW1[t] = W1[t];
    for (int t = tid; t < 128 * 20; t += 256) sA[t] = wsA[t];
    for (int t = tid; t < 64 * 20; t += 256) {
        int k = t / 20, j = t % 20;
        sWc2[t] = (j < 19) ? Wc2[k * 19 + j] : 0.f;
    }
    if (tid < 64) sb1[tid] = b1[tid];
    if (tid < 20) sc1[tid] = wsc1[tid];
    if (tid < 20) sbc2[tid] = (tid < 19) ? bc2[tid] : 0.f;
    __syncthreads();
    int i0 = blockIdx.x * 256 + tid;
    bool act = (i0 < NTOTP);
    int i = act ? i0 : 0;
    int b = i / NPTS;
    int2 hw = ((const int2*)idx)[i];
    float4 f14[16];
    #pragma unroll
    for (int c4 = 0; c4 < 16; ++c4) f14[c4] = ((const float4*)sb1)[c4];
    const float4* fu4 = (const float4*)(fusion + (size_t)i * NDIN);
    for (int d4 = 0; d4 < NDIN / 4; ++d4) {
        float4 x = fu4[d4];
        const float* wr = sW1 + d4 * 256;
        #pragma unroll
        for (int c4 = 0; c4 < 16; ++c4) {
            fma4o(f14[c4], x.x, *(const float4*)(wr + c4 * 4));
            fma4o(f14[c4], x.y, *(const float4*)(wr + 64 + c4 * 4));
            fma4o(f14[c4], x.z, *(const float4*)(wr + 128 + c4 * 4));
            fma4o(f14[c4], x.w, *(const float4*)(wr + 192 + c4 * 4));
        }
    }
    #pragma unroll
    for (int c4 = 0; c4 < 16; ++c4) {
        f14[c4].x = fmaxf(f14[c4].x, 0.f); f14[c4].y = fmaxf(f14[c4].y, 0.f);
        f14[c4].z = fmaxf(f14[c4].z, 0.f); f14[c4].w = fmaxf(f14[c4].w, 0.f);
    }
    float4 s14[5], s24[5];
    #pragma unroll
    for (int j4 = 0; j4 < 5; ++j4) { s14[j4] = ((const float4*)sc1)[j4]; s24[j4] = ((const float4*)sbc2)[j4]; }
    const float* fb = feats + (size_t)b * CHW_ + (size_t)hw.x * NWID + hw.y;
    for (int k = 0; k < 64; ++k) {
        float g = fb[(size_t)k * HW_];
        const float4* ar = (const float4*)(sA + k * 20);
        const float4* cr = (const float4*)(sWc2 + k * 20);
        #pragma unroll
        for (int j4 = 0; j4 < 5; ++j4) { fma4o(s14[j4], g, ar[j4]); fma4o(s24[j4], g, cr[j4]); }
    }
    const float* f1s = (const float*)f14;
    for (int k = 0; k < 64; ++k) {
        float g = f1s[k];
        const float4* ar = (const float4*)(sA + (64 + k) * 20);
        #pragma unroll
        for (int j4 = 0; j4 < 5; ++j4) fma4o(s14[j4], g, ar[j4]);
    }
    if (act) {
        float* o1 = out + (size_t)i * 19;
        float* o2 = out + (size_t)NTOTP * 19 + (size_t)i * 19;
        const float* s1s = (const float*)s14;
        const float* s2s = (const float*)s24;
        #pragma unroll
        for (int j = 0; j < 19; ++j) o1[j] = s1s[j];
        #pragma unroll
        for (int j = 0; j < 19; ++j) o2[j] = s2s[j];
    }
}

// ================= launch ====================================================
extern "C" void kernel_launch(void* const* d_in, const int* in_sizes, int n_in,
                              void* d_out, int out_size, void* d_ws, size_t ws_size,
                              hipStream_t stream) {
    const float* feats  = (const float*)d_in[0];
    const float* fusion = (const float*)d_in[1];
    const int*   idx    = (const int*)d_in[2];
    const float* W1  = (const float*)d_in[3];
    const float* b1  = (const float*)d_in[4];
    const float* W2  = (const float*)d_in[5];
    const float* b2  = (const float*)d_in[6];
    const float* Wc1 = (const float*)d_in[7];
    const float* bc1 = (const float*)d_in[8];
    const float* Wc2 = (const float*)d_in[9];
    const float* bc2 = (const float*)d_in[10];
    float* out = (float*)d_out;
    char* ws = (char*)d_ws;

    if (ws_size >= WS_NEED) {
        u16*   Wproj = (u16*)(ws + OFF_WPROJ);
        u16*   W1t   = (u16*)(ws + OFF_W1T);
        u16*   Wbot  = (u16*)(ws + OFF_WBOT);
        float* cbias = (float*)(ws + OFF_CBIAS);
        u16*   proj  = (u16*)(ws + OFF_PROJ);
        prep_kernel<<<45, 256, 0, stream>>>(W1, W2, b2, Wc1, bc1, Wc2, bc2,
                                            Wproj, W1t, Wbot, cbias);
        // MEASUREMENT: proj launched twice (idempotent — identical bytes).
        // total - 130.7us = proj marginal time. Will be removed next round.
        proj_kernel<<<PROJ_NWG, 256, 0, stream>>>(feats, Wproj, cbias, proj);
        proj_kernel<<<PROJ_NWG, 256, 0, stream>>>(feats, Wproj, cbias, proj);
        fused2_kernel<<<NTOTP / 128, 256, 0, stream>>>(fusion, idx, b1,
                                                       W1t, Wbot, proj, out);
    } else {
        float* wsA  = (float*)ws;
        float* wsc1 = wsA + 128 * 20;
        precompute_old<<<11, 256, 0, stream>>>(W2, b2, Wc1, bc1, wsA, wsc1);
        fused_old<<<(NTOTP + 255) / 256, 256, 0, stream>>>(feats, fusion, idx, W1, b1,
                                                           Wc2, bc2, wsA, wsc1, out);
    }
}

// Round 10
// 128.887 us; speedup vs baseline: 1.7976x; 1.6111x over previous
//
#include <hip/hip_runtime.h>

typedef unsigned int u32;
typedef unsigned short u16;
typedef unsigned long long u64;
typedef __attribute__((ext_vector_type(8))) short short8;
typedef __attribute__((ext_vector_type(4))) float f32x4;
typedef __attribute__((ext_vector_type(4))) float fv4;

#define NB 8
#define NC 64
#define NH 376
#define NWID 1241
#define NPTS 30000
#define NDIN 80
#define NTOTP 240000
#define PPB 141376              // 376*376 positions per sample
#define NPOS 1131008            // 8*PPB  (multiple of 256)
#define HW_ ((size_t)NH*NWID)
#define CHW_ ((size_t)NC*HW_)

// workspace layout (new path)
#define OFF_WPROJ 0             // u16[48*64]
#define OFF_W1T   8192          // u16[64*96]
#define OFF_WBOT  24576         // u16[32*64]
#define OFF_CBIAS 28672         // float[48]
#define OFF_PROJ  32768         // u16[NPOS][40]  (80B row per position)
#define WS_NEED   ((size_t)32768 + (size_t)NPOS*40*2)

__device__ __forceinline__ u16 f2bf(float f) {
    u32 u = __builtin_bit_cast(u32, f);
    return (u16)((u + 0x7FFFu + ((u >> 16) & 1u)) >> 16);
}
__device__ __forceinline__ float bf2f(u32 lo16) {
    return __builtin_bit_cast(float, lo16 << 16);
}
__device__ __forceinline__ u32 packbf2(float a, float b) {
    return (u32)f2bf(a) | ((u32)f2bf(b) << 16);
}
#define MFMA16(a,b,c) __builtin_amdgcn_mfma_f32_16x16x32_bf16(a, b, c, 0, 0, 0)

// ================= prep: build bf16 weight tables + folded biases ===========
__global__ void prep_kernel(const float* __restrict__ W1, const float* __restrict__ W2,
                            const float* __restrict__ b2, const float* __restrict__ Wc1,
                            const float* __restrict__ bc1, const float* __restrict__ Wc2,
                            const float* __restrict__ bc2,
                            u16* __restrict__ Wproj, u16* __restrict__ W1t,
                            u16* __restrict__ Wbot, float* __restrict__ cbias) {
    int t = blockIdx.x * 256 + threadIdx.x;
    if (t < 3072) {
        int j = t >> 6, ch = t & 63;
        float v = 0.f;
        if (j < 19) { for (int c = 0; c < 64; ++c) v += W2[ch * 64 + c] * Wc1[c * 19 + j]; }
        else if (j >= 20 && j < 39) v = Wc2[ch * 19 + (j - 20)];
        Wproj[t] = f2bf(v);
    } else if (t < 3072 + 6144) {
        int q = t - 3072; int c = q / 96, d = q % 96;
        W1t[q] = f2bf(d < 80 ? W1[d * 64 + c] : 0.f);
    } else if (t < 3072 + 6144 + 2048) {
        int q = t - 9216; int j = q >> 6, c = q & 63;
        float v = 0.f;
        if (j < 19) { for (int cc = 0; cc < 64; ++cc) v += W2[(64 + c) * 64 + cc] * Wc1[cc * 19 + j]; }
        Wbot[q] = f2bf(v);
    } else if (t < 3072 + 6144 + 2048 + 48) {
        int j = t - 11264;
        float v = 0.f;
        if (j < 19) { v = bc1[j]; for (int c = 0; c < 64; ++c) v += b2[c] * Wc1[c * 19 + j]; }
        else if (j >= 20 && j < 39) v = bc2[j - 20];
        cbias[j] = v;
    }
}

// ================= projection: block stages [64ch][256pos] in LDS ===========
#define PROJ_NWG (NPOS / 256)   // 4418
__global__ __launch_bounds__(256) void proj_kernel(const float* __restrict__ feats,
        const u16* __restrict__ Wproj, const float* __restrict__ cbias,
        u16* __restrict__ proj) {
    __shared__ __align__(16) u16 ldsA[64][264];   // 33.8 KB
    __shared__ __align__(16) u32 sst[4][16][20];  // 5 KB per-wave output staging
    int tid = threadIdx.x;
    int lane = tid & 63, wid = tid >> 6;
    int l15 = lane & 15, l4 = lane >> 4;
    // bijective XCD-aware swizzle (m204): q=nwg/8, r=nwg%8
    int orig = blockIdx.x;
    {
        const int q = PROJ_NWG / 8, r = PROJ_NWG % 8;
        int xcd = orig & 7, lid = orig >> 3;
        orig = (xcd < r ? xcd * (q + 1) : r * (q + 1) + (xcd - r) * q) + lid;
    }
    int pblk0 = orig * 256;

    // ---- stage: 16 channels per wave, 256 positions, one dwordx4 per lane/ch
    {
        u32 p0 = (u32)(pblk0 + lane * 4);
        u32 b = p0 / PPB;                 // float4-span never crosses b/h (PPB%4==0, 376%4==0)
        u32 r = p0 - b * PPB;
        u32 h = r / 376u, w = r - h * 376u;
        const float* base0 = feats + (size_t)b * CHW_ + (size_t)h * NWID + w;
        #pragma unroll
        for (int it = 0; it < 16; ++it) {
            int c = wid * 16 + it;
            fv4 v = __builtin_nontemporal_load((const fv4*)(base0 + (size_t)c * HW_));
            u64 pk = (u64)packbf2(v.x, v.y) | ((u64)packbf2(v.z, v.w) << 32);
            *(u64*)&ldsA[c][lane * 4] = pk;
        }
    }
    __syncthreads();

    // ---- weight fragments + bias
    short8 wf[3][2];
    #pragma unroll
    for (int mt = 0; mt < 3; ++mt)
        #pragma unroll
        for (int kt = 0; kt < 2; ++kt)
            wf[mt][kt] = *(const short8*)(Wproj + (mt * 16 + l15) * 64 + kt * 32 + l4 * 8);
    float bias[3][4];
    #pragma unroll
    for (int mt = 0; mt < 3; ++mt)
        #pragma unroll
        for (int q = 0; q < 4; ++q)
            bias[mt][q] = cbias[mt * 16 + l4 * 4 + q];

    // ---- compute: wave owns positions [wid*64, wid*64+64)
    #pragma unroll 1
    for (int nt = 0; nt < 4; ++nt) {
        int lp = wid * 64 + nt * 16 + l15;         // local position (this lane's column)
        short8 bfrag[2];
        #pragma unroll
        for (int kt = 0; kt < 2; ++kt) {
            int ch0 = kt * 32 + l4 * 8;
            short8 s;
            #pragma unroll
            for (int e = 0; e < 8; ++e) s[e] = (short)ldsA[ch0 + e][lp];
            bfrag[kt] = s;
        }
        f32x4 acc[3];
        #pragma unroll
        for (int mt = 0; mt < 3; ++mt) {
            f32x4 a = {bias[mt][0], bias[mt][1], bias[mt][2], bias[mt][3]};
            acc[mt] = a;
        }
        #pragma unroll
        for (int kt = 0; kt < 2; ++kt)
            #pragma unroll
            for (int mt = 0; mt < 3; ++mt)
                acc[mt] = MFMA16(wf[mt][kt], bfrag[kt], acc[mt]);
        // stage row slices into per-wave LDS: row l15, word mt*8+l4*2
        #pragma unroll
        for (int mt = 0; mt < 3; ++mt) {
            if (mt == 2 && l4 >= 2) continue;
            uint2 st;
            st.x = packbf2(acc[mt][0], acc[mt][1]);
            st.y = packbf2(acc[mt][2], acc[mt][3]);
            *(uint2*)&sst[wid][l15][mt * 8 + l4 * 2] = st;
        }
        // cooperative coalesced store: 16 rows x 80B = 1280B contiguous
        const u32* s0 = &sst[wid][0][0];
        u32* dst = (u32*)(proj + (size_t)(pblk0 + wid * 64 + nt * 16) * 40);
        #pragma unroll
        for (int s = 0; s < 5; ++s) dst[lane + s * 64] = s0[lane + s * 64];
    }
}

// ===== fused v2: batched loads (T14) — both nt groups' idx/gather/fusion
// loads issue upfront; fusion converts to bf16 early; compute back-to-back.
__global__ __launch_bounds__(256) void fused2_kernel(const float* __restrict__ fusion,
        const int* __restrict__ idx, const float* __restrict__ b1,
        const u16* __restrict__ W1t, const u16* __restrict__ Wbot,
        const u16* __restrict__ proj, float* __restrict__ out) {
    __shared__ __align__(16) u32 sbuf[4][16][44];
    int tid = threadIdx.x;
    int lane = tid & 63, wid = tid >> 6;
    int l15 = lane & 15, l4 = lane >> 4;
    int t = blockIdx.x * 4 + wid;                   // 7500 waves exactly
    int i0 = t * 32;

    short8 w1f[4][3];
    #pragma unroll
    for (int mt = 0; mt < 4; ++mt)
        #pragma unroll
        for (int kt = 0; kt < 3; ++kt)
            w1f[mt][kt] = *(const short8*)(W1t + (mt * 16 + l15) * 96 + kt * 32 + l4 * 8);
    short8 wbf[2][2];
    #pragma unroll
    for (int mt = 0; mt < 2; ++mt)
        #pragma unroll
        for (int kt = 0; kt < 2; ++kt)
            wbf[mt][kt] = *(const short8*)(Wbot + (mt * 16 + l15) * 64 + kt * 32 + l4 * 8);
    float b1r[4][4];
    #pragma unroll
    for (int mt = 0; mt < 4; ++mt)
        #pragma unroll
        for (int q = 0; q < 4; ++q)
            b1r[mt][q] = b1[mt * 16 + l4 * 4 + q];

    u32* myl = &sbuf[wid][0][0];

    // ---- phase 1: issue ALL loads for both 16-point groups
    u64 hv[2];
    #pragma unroll
    for (int nt = 0; nt < 2; ++nt)
        hv[nt] = __builtin_nontemporal_load((const u64*)idx + (i0 + nt * 16 + l15));

    uint2 g[2][3];
    #pragma unroll
    for (int nt = 0; nt < 2; ++nt) {
        int ip = i0 + nt * 16 + l15;
        u32 hh = (u32)hv[nt], ww = (u32)(hv[nt] >> 32);
        size_t pos = ((size_t)(u32)(ip / NPTS) * 376 + hh) * 376 + ww;
        const u16* prow = proj + pos * 40;
        #pragma unroll
        for (int mt = 0; mt < 3; ++mt)
            if (!(mt == 2 && l4 >= 2))
                g[nt][mt] = *(const uint2*)(prow + mt * 16 + l4 * 4);
    }

    fv4 fraw[2][6];
    #pragma unroll
    for (int nt = 0; nt < 2; ++nt) {
        const float* frow = fusion + (size_t)(i0 + nt * 16 + l15) * NDIN;
        #pragma unroll
        for (int kt = 0; kt < 3; ++kt) {
            int d0 = kt * 32 + l4 * 8;
            if (d0 < 80) {
                fraw[nt][kt * 2 + 0] = __builtin_nontemporal_load((const fv4*)(frow + d0));
                fraw[nt][kt * 2 + 1] = __builtin_nontemporal_load((const fv4*)(frow + d0 + 4));
            }
        }
    }

    // ---- phase 2: convert fusion to bf16 fragments (frees fp32 staging regs)
    short8 xf[2][3];
    #pragma unroll
    for (int nt = 0; nt < 2; ++nt)
        #pragma unroll
        for (int kt = 0; kt < 3; ++kt) {
            short8 s = {0, 0, 0, 0, 0, 0, 0, 0};
            int d0 = kt * 32 + l4 * 8;
            if (d0 < 80) {
                fv4 a = fraw[nt][kt * 2 + 0], bq = fraw[nt][kt * 2 + 1];
                s[0] = (short)f2bf(a.x);  s[1] = (short)f2bf(a.y);
                s[2] = (short)f2bf(a.z);  s[3] = (short)f2bf(a.w);
                s[4] = (short)f2bf(bq.x); s[5] = (short)f2bf(bq.y);
                s[6] = (short)f2bf(bq.z); s[7] = (short)f2bf(bq.w);
            }
            xf[nt][kt] = s;
        }

    // ---- phase 3: compute + store, both groups back-to-back
    #pragma unroll
    for (int nt = 0; nt < 2; ++nt) {
        int ipb = i0 + nt * 16;
        f32x4 acc[3];
        #pragma unroll
        for (int mt = 0; mt < 3; ++mt) {
            if (mt == 2 && l4 >= 2) { f32x4 z = {0.f, 0.f, 0.f, 0.f}; acc[mt] = z; }
            else {
                uint2 v = g[nt][mt];
                f32x4 a = {bf2f(v.x & 0xffffu), bf2f(v.x >> 16),
                           bf2f(v.y & 0xffffu), bf2f(v.y >> 16)};
                acc[mt] = a;
            }
        }
        f32x4 c1[4];
        #pragma unroll
        for (int mt = 0; mt < 4; ++mt) {
            f32x4 a = {b1r[mt][0], b1r[mt][1], b1r[mt][2], b1r[mt][3]};
            c1[mt] = a;
        }
        #pragma unroll
        for (int kt = 0; kt < 3; ++kt)
            #pragma unroll
            for (int mt = 0; mt < 4; ++mt) c1[mt] = MFMA16(w1f[mt][kt], xf[nt][kt], c1[mt]);
        // relu -> bf16 -> swizzled LDS rows
        #pragma unroll
        for (int mt = 0; mt < 4; ++mt) {
            float x0 = fmaxf(c1[mt][0], 0.f), x1 = fmaxf(c1[mt][1], 0.f);
            float x2 = fmaxf(c1[mt][2], 0.f), x3 = fmaxf(c1[mt][3], 0.f);
            u32 lo = packbf2(x0, x1), hi = packbf2(x2, x3);
            int c0 = mt * 16 + l4 * 4;
            int gsw = (c0 >> 3) ^ (l15 & 7);
            *(u64*)(myl + l15 * 44 + gsw * 4 + ((c0 & 4) >> 1)) = (u64)lo | ((u64)hi << 32);
        }
        #pragma unroll
        for (int kt = 0; kt < 2; ++kt) {
            int gsw = (kt * 4 + l4) ^ (l15 & 7);
            short8 f1f = *(const short8*)(myl + l15 * 44 + gsw * 4);
            #pragma unroll
            for (int mt = 0; mt < 2; ++mt) acc[mt] = MFMA16(wbf[mt][kt], f1f, acc[mt]);
        }
        #pragma unroll
        for (int mt = 0; mt < 3; ++mt) {
            if (mt == 2 && l4 >= 2) continue;
            *(f32x4*)(myl + l15 * 44 + mt * 16 + l4 * 4) = acc[mt];
        }
        size_t o1 = (size_t)ipb * 19;
        #pragma unroll
        for (int s = 0; s < 5; ++s) {
            int f = lane + s * 64;
            if (f < 304) {
                u32 rr = (u32)f / 19u;
                u32 jj = (u32)f - rr * 19u;
                float v1 = __builtin_bit_cast(float, myl[rr * 44 + jj]);
                float v2 = __builtin_bit_cast(float, myl[rr * 44 + 20 + jj]);
                __builtin_nontemporal_store(v1, out + o1 + f);
                __builtin_nontemporal_store(v2, out + (size_t)NTOTP * 19 + o1 + f);
            }
        }
    }
}

// ================= fallback (tiny ws): direct path ==========================
__global__ void precompute_old(const float* __restrict__ W2, const float* __restrict__ b2,
                               const float* __restrict__ Wc1, const float* __restrict__ bc1,
                               float* __restrict__ wsA, float* __restrict__ wsc1) {
    int t = blockIdx.x * 256 + threadIdx.x;
    if (t < 128 * 20) {
        int k = t / 20, j = t % 20;
        float v = 0.f;
        if (j < 19) for (int c = 0; c < 64; ++c) v += W2[k * 64 + c] * Wc1[c * 19 + j];
        wsA[t] = v;
    } else if (t < 128 * 20 + 20) {
        int j = t - 128 * 20;
        float v = 0.f;
        if (j < 19) { v = bc1[j]; for (int c = 0; c < 64; ++c) v += b2[c] * Wc1[c * 19 + j]; }
        wsc1[j] = v;
    }
}

__device__ __forceinline__ void fma4o(float4& a, float s, const float4 b) {
    a.x = fmaf(s, b.x, a.x); a.y = fmaf(s, b.y, a.y);
    a.z = fmaf(s, b.z, a.z); a.w = fmaf(s, b.w, a.w);
}

__global__ __launch_bounds__(256) void fused_old(
    const float* __restrict__ feats, const float* __restrict__ fusion,
    const int* __restrict__ idx, const float* __restrict__ W1, const float* __restrict__ b1,
    const float* __restrict__ Wc2, const float* __restrict__ bc2,
    const float* __restrict__ wsA, const float* __restrict__ wsc1, float* __restrict__ out) {
    __shared__ __align__(16) float sW1[80 * 64];
    __shared__ __align__(16) float sA[128 * 20];
    __shared__ __align__(16) float sWc2[64 * 20];
    __shared__ __align__(16) float sb1[64];
    __shared__ __align__(16) float sc1[20];
    __shared__ __align__(16) float sbc2[20];
    int tid = threadIdx.x;
    for (int t = tid; t < 80 * 64; t += 256) sW1[t] = W1[t];
    for (int t = tid; t < 128 * 20; t += 256) sA[t] = wsA[t];
    for (int t = tid; t < 64 * 20; t += 256) {
        int k = t / 20, j = t % 20;
        sWc2[t] = (j < 19) ? Wc2[k * 19 + j] : 0.f;
    }
    if (tid < 64) sb1[tid] = b1[tid];
    if (tid < 20) sc1[tid] = wsc1[tid];
    if (tid < 20) sbc2[tid] = (tid < 19) ? bc2[tid] : 0.f;
    __syncthreads();
    int i0 = blockIdx.x * 256 + tid;
    bool act = (i0 < NTOTP);
    int i = act ? i0 : 0;
    int b = i / NPTS;
    int2 hw = ((const int2*)idx)[i];
    float4 f14[16];
    #pragma unroll
    for (int c4 = 0; c4 < 16; ++c4) f14[c4] = ((const float4*)sb1)[c4];
    const float4* fu4 = (const float4*)(fusion + (size_t)i * NDIN);
    for (int d4 = 0; d4 < NDIN / 4; ++d4) {
        float4 x = fu4[d4];
        const float* wr = sW1 + d4 * 256;
        #pragma unroll
        for (int c4 = 0; c4 < 16; ++c4) {
            fma4o(f14[c4], x.x, *(const float4*)(wr + c4 * 4));
            fma4o(f14[c4], x.y, *(const float4*)(wr + 64 + c4 * 4));
            fma4o(f14[c4], x.z, *(const float4*)(wr + 128 + c4 * 4));
            fma4o(f14[c4], x.w, *(const float4*)(wr + 192 + c4 * 4));
        }
    }
    #pragma unroll
    for (int c4 = 0; c4 < 16; ++c4) {
        f14[c4].x = fmaxf(f14[c4].x, 0.f); f14[c4].y = fmaxf(f14[c4].y, 0.f);
        f14[c4].z = fmaxf(f14[c4].z, 0.f); f14[c4].w = fmaxf(f14[c4].w, 0.f);
    }
    float4 s14[5], s24[5];
    #pragma unroll
    for (int j4 = 0; j4 < 5; ++j4) { s14[j4] = ((const float4*)sc1)[j4]; s24[j4] = ((const float4*)sbc2)[j4]; }
    const float* fb = feats + (size_t)b * CHW_ + (size_t)hw.x * NWID + hw.y;
    for (int k = 0; k < 64; ++k) {
        float g = fb[(size_t)k * HW_];
        const float4* ar = (const float4*)(sA + k * 20);
        const float4* cr = (const float4*)(sWc2 + k * 20);
        #pragma unroll
        for (int j4 = 0; j4 < 5; ++j4) { fma4o(s14[j4], g, ar[j4]); fma4o(s24[j4], g, cr[j4]); }
    }
    const float* f1s = (const float*)f14;
    for (int k = 0; k < 64; ++k) {
        float g = f1s[k];
        const float4* ar = (const float4*)(sA + (64 + k) * 20);
        #pragma unroll
        for (int j4 = 0; j4 < 5; ++j4) fma4o(s14[j4], g, ar[j4]);
    }
    if (act) {
        float* o1 = out + (size_t)i * 19;
        float* o2 = out + (size_t)NTOTP * 19 + (size_t)i * 19;
        const float* s1s = (const float*)s14;
        const float* s2s = (const float*)s24;
        #pragma unroll
        for (int j = 0; j < 19; ++j) o1[j] = s1s[j];
        #pragma unroll
        for (int j = 0; j < 19; ++j) o2[j] = s2s[j];
    }
}

// ================= launch ====================================================
extern "C" void kernel_launch(void* const* d_in, const int* in_sizes, int n_in,
                              void* d_out, int out_size, void* d_ws, size_t ws_size,
                              hipStream_t stream) {
    const float* feats  = (const float*)d_in[0];
    const float* fusion = (const float*)d_in[1];
    const int*   idx    = (const int*)d_in[2];
    const float* W1  = (const float*)d_in[3];
    const float* b1  = (const float*)d_in[4];
    const float* W2  = (const float*)d_in[5];
    const float* b2  = (const float*)d_in[6];
    const float* Wc1 = (const float*)d_in[7];
    const float* bc1 = (const float*)d_in[8];
    const float* Wc2 = (const float*)d_in[9];
    const float* bc2 = (const float*)d_in[10];
    float* out = (float*)d_out;
    char* ws = (char*)d_ws;

    if (ws_size >= WS_NEED) {
        u16*   Wproj = (u16*)(ws + OFF_WPROJ);
        u16*   W1t   = (u16*)(ws + OFF_W1T);
        u16*   Wbot  = (u16*)(ws + OFF_WBOT);
        float* cbias = (float*)(ws + OFF_CBIAS);
        u16*   proj  = (u16*)(ws + OFF_PROJ);
        prep_kernel<<<45, 256, 0, stream>>>(W1, W2, b2, Wc1, bc1, Wc2, bc2,
                                            Wproj, W1t, Wbot, cbias);
        proj_kernel<<<PROJ_NWG, 256, 0, stream>>>(feats, Wproj, cbias, proj);
        fused2_kernel<<<NTOTP / 128, 256, 0, stream>>>(fusion, idx, b1,
                                                       W1t, Wbot, proj, out);
    } else {
        float* wsA  = (float*)ws;
        float* wsc1 = wsA + 128 * 20;
        precompute_old<<<11, 256, 0, stream>>>(W2, b2, Wc1, bc1, wsA, wsc1);
        fused_old<<<(NTOTP + 255) / 256, 256, 0, stream>>>(feats, fusion, idx, W1, b1,
                                                           Wc2, bc2, wsA, wsc1, out);
    }
}